// Round 2
// baseline (238.341 us; speedup 1.0000x reference)
//
#include <hip/hip_runtime.h>

// Problem constants
#define NB 16          // batch
#define NV 8           // vars per sample
#define HW 512         // H = W
#define PH 16          // patch h = w
#define GH 32          // grid h = w (512/16)
#define ED 128         // embed dim
#define KD 256         // 16*16 patch elems
#define MAXV 10

typedef __bf16 bf16x8 __attribute__((ext_vector_type(8)));
typedef float  f32x4  __attribute__((ext_vector_type(4)));

// ---------------------------------------------------------------------------
// Pack fp32 weights -> bf16 in B-fragment order:
//   packed[var*32768 + kb*4096 + n*32 + t]  where k = kb*32 + t, t = quad*8 + j
// Lane l of the main kernel reads bf16x8 at
//   var*32768 + kb*4096 + (n0 + (l&15))*32 + (l>>4)*8   (16B aligned, wave
// covers 2 KB contiguous -> coalesced, L2-resident: 640 KB total).
// ---------------------------------------------------------------------------
__global__ __launch_bounds__(256) void pack_weights(const float* __restrict__ w,
                                                    __bf16* __restrict__ packed) {
    int tid = blockIdx.x * 256 + threadIdx.x;
    if (tid >= MAXV * ED * KD) return;
    int t   = tid & 31;
    int n   = (tid >> 5) & 127;
    int kb  = (tid >> 12) & 7;
    int var = tid >> 15;
    int k   = kb * 32 + t;
    float f = w[(var * ED + n) * KD + k];
    packed[tid] = (__bf16)f;
}

// ---------------------------------------------------------------------------
// Main kernel, v2: NO LDS, NO barrier.
// One block per (b, v, h-strip); 4 waves, each computes 32(patch) x 32(emb).
// A-fragment trick: for 16x16x32 bf16 MFMA, lane (lo,quad) needs
//   A[m = i*16+lo][k = kb*32 + quad*8 .. +7]
// and k -> (p = k>>4, q = k&15) means those 8 elements are x[p][m*16+q0..+7]
// = 32 CONTIGUOUS bytes of x. So each lane loads its fragment directly from
// global (2x dwordx4 + cvt) -- no staging, no sync. The 4x cross-wave
// redundancy of the 32 KB strip is served by L1 (32 KB) / L2.
// ---------------------------------------------------------------------------
__global__ __launch_bounds__(256, 4) void patch_embed(
    const float* __restrict__ x,
    const int*   __restrict__ in_vars,
    const __bf16* __restrict__ wpacked,
    const float* __restrict__ bias,
    float* __restrict__ out)
{
    const int bx  = blockIdx.x;
    const int h   = bx & 31;
    const int v   = (bx >> 5) & 7;
    const int b   = bx >> 8;
    const int tid = threadIdx.x;

    const int wave = tid >> 6;
    const int lane = tid & 63;
    const int lo   = lane & 15;
    const int quad = lane >> 4;
    const int nwave = wave * 32;       // this wave's emb-column base

    const int var = in_vars[v];

    const float* xb = x + (((size_t)(b * NV + v)) * HW + (size_t)h * PH) * HW;
    const __bf16* wbase = wpacked + (size_t)var * (ED * KD);

    // ---- hoist all B fragments into registers (L2-hit loads, 64 VGPRs) ----
    bf16x8 bF[8][2];
    #pragma unroll
    for (int kb = 0; kb < 8; ++kb)
        #pragma unroll
        for (int j = 0; j < 2; ++j)
            bF[kb][j] = *(const bf16x8*)&wbase[kb * 4096 + (nwave + j * 16 + lo) * 32 + quad * 8];

    f32x4 acc[2][2];
    #pragma unroll
    for (int i = 0; i < 2; ++i)
        #pragma unroll
        for (int j = 0; j < 2; ++j)
            acc[i][j] = (f32x4){0.f, 0.f, 0.f, 0.f};

    // per-lane A base: row p0 = quad>>1, col = lo*16 + (quad&1)*8
    const float* abase = xb + (size_t)(quad >> 1) * HW + lo * PH + (quad & 1) * 8;

    #pragma unroll
    for (int kb = 0; kb < 8; ++kb) {
        bf16x8 aF[2];
        #pragma unroll
        for (int i = 0; i < 2; ++i) {
            const float* pA = abase + (size_t)(2 * kb) * HW + i * 256;  // i*16 patches * 16 cols
            float4 f0 = *(const float4*)pA;
            float4 f1 = *(const float4*)(pA + 4);
            bf16x8 t;
            t[0] = (__bf16)f0.x; t[1] = (__bf16)f0.y; t[2] = (__bf16)f0.z; t[3] = (__bf16)f0.w;
            t[4] = (__bf16)f1.x; t[5] = (__bf16)f1.y; t[6] = (__bf16)f1.z; t[7] = (__bf16)f1.w;
            aF[i] = t;
        }
        #pragma unroll
        for (int i = 0; i < 2; ++i)
            #pragma unroll
            for (int j = 0; j < 2; ++j)
                acc[i][j] = __builtin_amdgcn_mfma_f32_16x16x32_bf16(aF[i], bF[kb][j], acc[i][j], 0, 0, 0);
    }

    // ---- epilogue: C/D layout col = lane&15, row = quad*4 + reg (m89) ----
    float bv[2];
    #pragma unroll
    for (int j = 0; j < 2; ++j)
        bv[j] = bias[var * ED + nwave + j * 16 + lo];

    const size_t outbase = ((size_t)(b * NV + v)) * (GH * GH) + (size_t)h * GH;
    #pragma unroll
    for (int i = 0; i < 2; ++i) {
        #pragma unroll
        for (int r = 0; r < 4; ++r) {
            int m = i * 16 + quad * 4 + r;   // patch w index
            #pragma unroll
            for (int j = 0; j < 2; ++j) {
                int e = nwave + j * 16 + lo;
                out[(outbase + m) * ED + e] = acc[i][j][r] + bv[j];
            }
        }
    }
}

extern "C" void kernel_launch(void* const* d_in, const int* in_sizes, int n_in,
                              void* d_out, int out_size, void* d_ws, size_t ws_size,
                              hipStream_t stream) {
    const float* x       = (const float*)d_in[0];
    const int*   in_vars = (const int*)d_in[1];
    const float* w       = (const float*)d_in[2];
    const float* bias    = (const float*)d_in[3];
    float*       out     = (float*)d_out;
    __bf16*      wpacked = (__bf16*)d_ws;   // 655,360 B needed

    hipLaunchKernelGGL(pack_weights, dim3((MAXV * ED * KD + 255) / 256), dim3(256), 0, stream,
                       w, wpacked);
    hipLaunchKernelGGL(patch_embed, dim3(NB * NV * GH), dim3(256), 0, stream,
                       x, in_vars, wpacked, bias, out);
}

// Round 3
// 220.854 us; speedup vs baseline: 1.0792x; 1.0792x over previous
//
#include <hip/hip_runtime.h>

// Problem constants
#define NB 16          // batch
#define NV 8           // vars per sample
#define HW 512         // H = W
#define PH 16          // patch h = w
#define GH 32          // grid h = w (512/16)
#define ED 128         // embed dim
#define KD 256         // 16*16 patch elems
#define MAXV 10

typedef __bf16 bf16x8 __attribute__((ext_vector_type(8)));
typedef float  f32x4  __attribute__((ext_vector_type(4)));

// ---------------------------------------------------------------------------
// Pack fp32 weights -> bf16 in B-fragment order:
//   packed[var*32768 + kb*4096 + n*32 + t]  where k = kb*32 + t, t = quad*8 + j
// Main kernel lane l reads bf16x8 at
//   var*32768 + kb*4096 + (n0 + (l&15))*32 + (l>>4)*8   (16B aligned, wave
// covers 2 KB contiguous -> coalesced; 640 KB total -> L2-resident).
// ---------------------------------------------------------------------------
__global__ __launch_bounds__(256) void pack_weights(const float* __restrict__ w,
                                                    __bf16* __restrict__ packed) {
    int tid = blockIdx.x * 256 + threadIdx.x;
    if (tid >= MAXV * ED * KD) return;
    int t   = tid & 31;
    int n   = (tid >> 5) & 127;
    int kb  = (tid >> 12) & 7;
    int var = tid >> 15;
    int k   = kb * 32 + t;
    float f = w[(var * ED + n) * KD + k];
    packed[tid] = (__bf16)f;
}

// ---------------------------------------------------------------------------
// Main kernel, v3: async global_load_lds staging (VGPR-pressure-immune MLP).
//
// Round-2 lesson: compiler allocated only 32 VGPRs and serialized the load
// stream -> ~4 loads in flight/wave -> 1.6 TB/s (latency-bound). The DMA
// path needs NO destination VGPRs: 8 x 1KB async copies per wave, 4 blocks
// resident per CU -> up to 128 KB outstanding per CU during staging.
//
// LDS holds the 16x512 fp32 strip as an EXACT mirror of global (the strip is
// one contiguous 32 KB range of x; global_load_lds writes wave-uniform base
// + lane*16, so no padding allowed). A-fragments: 8 consecutive fp32 per
// lane (2 x ds_read_b128, 32B-aligned) + cvt to bf16.
// ---------------------------------------------------------------------------
__global__ __launch_bounds__(256, 4) void patch_embed(
    const float* __restrict__ x,
    const int*   __restrict__ in_vars,
    const __bf16* __restrict__ wpacked,
    const float* __restrict__ bias,
    float* __restrict__ out)
{
    __shared__ float As[PH * HW];   // 32 KB, exact mirror of the strip

    const int bx  = blockIdx.x;
    const int h   = bx & 31;
    const int v   = (bx >> 5) & 7;
    const int b   = bx >> 8;
    const int tid = threadIdx.x;

    const int wave = tid >> 6;
    const int lane = tid & 63;
    const int lo   = lane & 15;
    const int quad = lane >> 4;
    const int nwave = wave * 32;       // this wave's emb-column base

    const int var = in_vars[v];

    // strip = rows [h*16, h*16+16) of x[b][v] -> contiguous 32 KB
    const float* xb = x + (((size_t)(b * NV + v)) * HW + (size_t)h * PH) * HW;

    // ---- async DMA: wave w copies bytes [w*8K, w*8K+8K) of the strip ----
    {
        const char* g0 = (const char*)xb + wave * 8192 + lane * 16;
        #pragma unroll
        for (int t = 0; t < 8; ++t) {
            __builtin_amdgcn_global_load_lds(
                (const __attribute__((address_space(1))) void*)(g0 + t * 1024),
                (__attribute__((address_space(3))) void*)((char*)As + wave * 8192 + t * 1024),
                16, 0, 0);
        }
    }

    // ---- B fragments (bf16, packed order, L2-resident) ----
    const __bf16* wbase = wpacked + (size_t)var * (ED * KD);
    bf16x8 bF[8][2];
    #pragma unroll
    for (int kb = 0; kb < 8; ++kb)
        #pragma unroll
        for (int j = 0; j < 2; ++j)
            bF[kb][j] = *(const bf16x8*)&wbase[kb * 4096 + (nwave + j * 16 + lo) * 32 + quad * 8];

    __syncthreads();   // drains the DMA (vmcnt) + barrier

    f32x4 acc[2][2];
    #pragma unroll
    for (int i = 0; i < 2; ++i)
        #pragma unroll
        for (int j = 0; j < 2; ++j)
            acc[i][j] = (f32x4){0.f, 0.f, 0.f, 0.f};

    // A[m][k] = x[p][m*16+q], k = p*16+q. Fragment (kb,i), lane (lo,quad):
    //   p = 2*kb + (quad>>1), floats [ (i*16+lo)*16 + (quad&1)*8 .. +7 ]
    #pragma unroll
    for (int kb = 0; kb < 8; ++kb) {
        bf16x8 aF[2];
        #pragma unroll
        for (int i = 0; i < 2; ++i) {
            int f = (2 * kb + (quad >> 1)) * HW + (i * 16 + lo) * PH + (quad & 1) * 8;
            float4 f0 = *(const float4*)&As[f];
            float4 f1 = *(const float4*)&As[f + 4];
            bf16x8 t;
            t[0] = (__bf16)f0.x; t[1] = (__bf16)f0.y; t[2] = (__bf16)f0.z; t[3] = (__bf16)f0.w;
            t[4] = (__bf16)f1.x; t[5] = (__bf16)f1.y; t[6] = (__bf16)f1.z; t[7] = (__bf16)f1.w;
            aF[i] = t;
        }
        #pragma unroll
        for (int i = 0; i < 2; ++i)
            #pragma unroll
            for (int j = 0; j < 2; ++j)
                acc[i][j] = __builtin_amdgcn_mfma_f32_16x16x32_bf16(aF[i], bF[kb][j], acc[i][j], 0, 0, 0);
    }

    // ---- epilogue: C/D layout col = lane&15, row = quad*4 + reg (m89) ----
    float bv[2];
    #pragma unroll
    for (int j = 0; j < 2; ++j)
        bv[j] = bias[var * ED + nwave + j * 16 + lo];

    const size_t outbase = ((size_t)(b * NV + v)) * (GH * GH) + (size_t)h * GH;
    #pragma unroll
    for (int i = 0; i < 2; ++i) {
        #pragma unroll
        for (int r = 0; r < 4; ++r) {
            int m = i * 16 + quad * 4 + r;   // patch w index
            #pragma unroll
            for (int j = 0; j < 2; ++j) {
                int e = nwave + j * 16 + lo;
                out[(outbase + m) * ED + e] = acc[i][j][r] + bv[j];
            }
        }
    }
}

extern "C" void kernel_launch(void* const* d_in, const int* in_sizes, int n_in,
                              void* d_out, int out_size, void* d_ws, size_t ws_size,
                              hipStream_t stream) {
    const float* x       = (const float*)d_in[0];
    const int*   in_vars = (const int*)d_in[1];
    const float* w       = (const float*)d_in[2];
    const float* bias    = (const float*)d_in[3];
    float*       out     = (float*)d_out;
    __bf16*      wpacked = (__bf16*)d_ws;   // 655,360 B needed

    hipLaunchKernelGGL(pack_weights, dim3((MAXV * ED * KD + 255) / 256), dim3(256), 0, stream,
                       w, wpacked);
    hipLaunchKernelGGL(patch_embed, dim3(NB * NV * GH), dim3(256), 0, stream,
                       x, in_vars, wpacked, bias, out);
}

// Round 4
// 219.601 us; speedup vs baseline: 1.0853x; 1.0057x over previous
//
#include <hip/hip_runtime.h>

// Problem constants
#define NB 16          // batch
#define NV 8           // vars per sample
#define HW 512         // H = W
#define PH 16          // patch h = w
#define GH 32          // grid h = w (512/16)
#define ED 128         // embed dim
#define KD 256         // 16*16 patch elems
#define MAXV 10

typedef __bf16 bf16x8 __attribute__((ext_vector_type(8)));
typedef float  f32x4  __attribute__((ext_vector_type(4)));

// gfx9 waitcnt imm: vmcnt -> bits [3:0] and [15:14]; exp=0x7, lgkm=0xF (no wait)
template<int N> __device__ __forceinline__ void waitvm() {
    __builtin_amdgcn_s_waitcnt(0x0F70 | (N & 0xF) | ((N >> 4) << 14));
}

// ---------------------------------------------------------------------------
// Pack fp32 weights -> bf16 in B-fragment order:
//   packed[var*32768 + kb*4096 + n*32 + t], k = kb*32 + t, t = quad*8 + j
// (verified correct in rounds 1-3)
// ---------------------------------------------------------------------------
__global__ __launch_bounds__(256) void pack_weights(const float* __restrict__ w,
                                                    __bf16* __restrict__ packed) {
    int tid = blockIdx.x * 256 + threadIdx.x;
    if (tid >= MAXV * ED * KD) return;
    int t   = tid & 31;
    int n   = (tid >> 5) & 127;
    int kb  = (tid >> 12) & 7;
    int var = tid >> 15;
    int k   = kb * 32 + t;
    float f = w[(var * ED + n) * KD + k];
    packed[tid] = (__bf16)f;
}

// ---------------------------------------------------------------------------
// v4: barrier-free per-wave streaming pipeline.
// One WAVE = one strip (32 patches x 128 emb). Private LDS ring: 4 stages x
// 4 KB (= 2 x-rows) filled by global_load_lds; B fragments in a 3-deep
// register ring prefetched from L2-resident packed weights. Hand vmcnt(N)
// per K-step; no __syncthreads anywhere.
//
// Issue stream per wave:  D0 D1 D2 D3 | B0 B1 | it_k: [wait N_k; compute k;
// issue B(k+2); issue D(k+4)].  N_k = ops issued after the later of
// {D(k), B(k)} = {8,12,16,16,16,12,8,0}.  asm memory clobbers pin the load
// placement so these counts remain valid.
// ---------------------------------------------------------------------------
__global__ __launch_bounds__(256, 2) void patch_embed(
    const float* __restrict__ x,
    const int*   __restrict__ in_vars,
    const __bf16* __restrict__ wpacked,
    const float* __restrict__ bias,
    float* __restrict__ out)
{
    __shared__ float As[4 * 1024 * 4];   // 4 waves x (4 stages x 1024 floats) = 64 KB

    const int tid  = threadIdx.x;
    const int wv   = tid >> 6;
    const int lane = tid & 63;
    const int lo   = lane & 15;
    const int quad = lane >> 4;
    const int qh   = quad >> 1;
    const int qlo  = quad & 1;

    // strip id: 4 strips per block, same (b,v) across the block's waves
    const int sid = blockIdx.x * 4 + wv;
    const int h   = sid & 31;
    const int v   = (sid >> 5) & 7;
    const int b   = sid >> 8;

    const int var = in_vars[v];

    const char* xstrip = (const char*)(x + (((size_t)(b * NV + v)) * HW + (size_t)h * PH) * HW);
    const __bf16* wbase = wpacked + (size_t)var * (ED * KD);

    // ---- DMA one 4 KB stage (2 x-rows) into this wave's ring slot ----
#define DMA_STAGE(T) { \
        const char* gsrc = xstrip + (T) * 4096 + lane * 16; \
        char* lbase = (char*)As + wv * 16384 + ((T) & 3) * 4096; \
        _Pragma("unroll") for (int c = 0; c < 4; ++c) \
            __builtin_amdgcn_global_load_lds( \
                (const __attribute__((address_space(1))) void*)(gsrc + c * 1024), \
                (__attribute__((address_space(3))) void*)(lbase + c * 1024), 16, 0, 0); }

    // ---- load one B k-block (8 frags) into register-ring set (T)%3 ----
#define BLOAD(T) { \
        _Pragma("unroll") for (int j = 0; j < 8; ++j) \
            bF[(T) % 3][j] = *(const bf16x8*)&wbase[(T) * 4096 + (j * 16 + lo) * 32 + quad * 8]; }

    bf16x8 bF[3][8];
    f32x4  acc[2][8];
    #pragma unroll
    for (int i = 0; i < 2; ++i)
        #pragma unroll
        for (int j = 0; j < 8; ++j)
            acc[i][j] = (f32x4){0.f, 0.f, 0.f, 0.f};

    // ---- prologue: fill LDS ring (4 stages) + first 2 B sets ----
    DMA_STAGE(0); DMA_STAGE(1); DMA_STAGE(2); DMA_STAGE(3);
    asm volatile("" ::: "memory");
    BLOAD(0); BLOAD(1);
    asm volatile("" ::: "memory");

    // ---- K-loop: 8 steps, fully unrolled with static vmcnt counts ----
#define A_ITER(KB, NW) { \
        waitvm<NW>(); \
        asm volatile("" ::: "memory"); \
        const float* st = As + wv * 4096 + ((KB) & 3) * 1024; \
        bf16x8 aF[2]; \
        _Pragma("unroll") for (int i = 0; i < 2; ++i) { \
            int fo = qh * 512 + (i * 16 + lo) * 16 + qlo * 8; \
            f32x4 r0 = *(const f32x4*)&st[fo]; \
            f32x4 r1 = *(const f32x4*)&st[fo + 4]; \
            bf16x8 t; \
            t[0] = (__bf16)r0.x; t[1] = (__bf16)r0.y; t[2] = (__bf16)r0.z; t[3] = (__bf16)r0.w; \
            t[4] = (__bf16)r1.x; t[5] = (__bf16)r1.y; t[6] = (__bf16)r1.z; t[7] = (__bf16)r1.w; \
            aF[i] = t; } \
        _Pragma("unroll") for (int i = 0; i < 2; ++i) \
            _Pragma("unroll") for (int j = 0; j < 8; ++j) \
                acc[i][j] = __builtin_amdgcn_mfma_f32_16x16x32_bf16(aF[i], bF[(KB) % 3][j], acc[i][j], 0, 0, 0); \
        asm volatile("" ::: "memory"); \
        if ((KB) + 2 < 8) BLOAD((KB) + 2); \
        if ((KB) + 4 < 8) DMA_STAGE((KB) + 4); \
        asm volatile("" ::: "memory"); }

    A_ITER(0, 8)
    A_ITER(1, 12)
    A_ITER(2, 16)
    A_ITER(3, 16)
    A_ITER(4, 16)
    A_ITER(5, 12)
    A_ITER(6, 8)
    A_ITER(7, 0)

#undef A_ITER
#undef BLOAD
#undef DMA_STAGE

    // ---- epilogue: C/D layout col = lane&15, row = quad*4 + reg (m89) ----
    float bv_[8];
    #pragma unroll
    for (int j = 0; j < 8; ++j)
        bv_[j] = bias[var * ED + j * 16 + lo];

    const size_t outbase = ((size_t)(b * NV + v)) * (GH * GH) + (size_t)h * GH;
    #pragma unroll
    for (int i = 0; i < 2; ++i) {
        #pragma unroll
        for (int r = 0; r < 4; ++r) {
            int m = i * 16 + quad * 4 + r;   // patch index within strip
            #pragma unroll
            for (int j = 0; j < 8; ++j) {
                out[(outbase + m) * ED + j * 16 + lo] = acc[i][j][r] + bv_[j];
            }
        }
    }
}

extern "C" void kernel_launch(void* const* d_in, const int* in_sizes, int n_in,
                              void* d_out, int out_size, void* d_ws, size_t ws_size,
                              hipStream_t stream) {
    const float* x       = (const float*)d_in[0];
    const int*   in_vars = (const int*)d_in[1];
    const float* w       = (const float*)d_in[2];
    const float* bias    = (const float*)d_in[3];
    float*       out     = (float*)d_out;
    __bf16*      wpacked = (__bf16*)d_ws;   // 655,360 B needed

    hipLaunchKernelGGL(pack_weights, dim3((MAXV * ED * KD + 255) / 256), dim3(256), 0, stream,
                       w, wpacked);
    hipLaunchKernelGGL(patch_embed, dim3(NB * NV * GH / 4), dim3(256), 0, stream,
                       x, in_vars, wpacked, bias, out);
}